// Round 18
// baseline (330.857 us; speedup 1.0000x reference)
//
#include <hip/hip_runtime.h>
#include <stdint.h>

// Shapes (fixed): B=4 L=2048 D=2048 H=16 KVH=4 HD=128 M=16 T=2032
typedef unsigned short u16;
typedef short s8v __attribute__((ext_vector_type(8)));   // 8 bf16 (4 VGPR) MFMA frag
typedef float f4v __attribute__((ext_vector_type(4)));   // 16x16 MFMA accum
typedef float f16v __attribute__((ext_vector_type(16))); // 32x32 MFMA accum

typedef __attribute__((address_space(1))) char gchar;
typedef __attribute__((address_space(3))) char lchar;

static __device__ __forceinline__ u16 f2bf(float f) {
  uint32_t x = __float_as_uint(f);
  x += 0x7fffu + ((x >> 16) & 1u);            // RNE
  return (u16)(x >> 16);
}
static __device__ __forceinline__ float bf2f(u16 u) {
  return __uint_as_float(((uint32_t)u) << 16);
}
// async global->LDS, 16B per lane. LDS dest must be wave-linear (base + lane*16).
static __device__ __forceinline__ void gload_lds16(const void* g, void* l) {
  __builtin_amdgcn_global_load_lds((gchar*)(uintptr_t)g,
                                   (lchar*)(uint32_t)(uintptr_t)l, 16, 0, 0);
}

// ---------------- prep: x->bf16, weights->bf16, rope table (one launch) ----------------
__global__ __launch_bounds__(256) void prep(const float4* __restrict__ x,
                                            const float4* __restrict__ wq,
                                            const float4* __restrict__ wk,
                                            const float4* __restrict__ wv,
                                            const float4* __restrict__ wp,
                                            uint2* __restrict__ xbf,
                                            uint2* __restrict__ wbf,
                                            float* __restrict__ tc,
                                            float* __restrict__ ts) {
  const int gid = blockIdx.x * 256 + threadIdx.x;
  const int st = gridDim.x * 256;
  for (int i = gid; i < 4194304; i += st) {            // x: 8192x2048 fp32
    float4 v = x[i];
    uint2 o;
    o.x = (uint32_t)f2bf(v.x) | ((uint32_t)f2bf(v.y) << 16);
    o.y = (uint32_t)f2bf(v.z) | ((uint32_t)f2bf(v.w) << 16);
    xbf[i] = o;
  }
  for (int i = gid; i < 2621440; i += st) {            // wq|wk|wv|wp contiguous dst
    const float4* s;
    int off;
    if (i < 1048576)      { s = wq; off = i; }
    else if (i < 1310720) { s = wk; off = i - 1048576; }
    else if (i < 1572864) { s = wv; off = i - 1310720; }
    else                  { s = wp; off = i - 1572864; }
    float4 v = s[off];
    uint2 o;
    o.x = (uint32_t)f2bf(v.x) | ((uint32_t)f2bf(v.y) << 16);
    o.y = (uint32_t)f2bf(v.z) | ((uint32_t)f2bf(v.w) << 16);
    wbf[i] = o;
  }
  for (int i = gid; i < 2032 * 64; i += st) {          // rope table [T][64]
    int t = i >> 6, f = i & 63;
    float invf = 1.0f / powf(10000.0f, (float)f * (1.0f / 64.0f));
    float ang = (float)t * invf;
    float s, c;
    sincosf(ang, &s, &c);
    tc[i] = c;
    ts[i] = s;
  }
}

// ---------------- gemm v3: 256x128 tile, 4 waves, 2 blocks/CU ----------------
// R17 root-cause: wave-tile 128x64 needs ~220 regs -> 2 waves/SIMD cap; with
// 512-thr blocks that is ONE barrier domain per CU -> every s_barrier stalls
// the whole CU. v3: 256 threads = 4 waves (2M x 2N, wave-tile 128x64 kept),
// BK=32 2-slot dbuf, 48KB LDS -> TWO independent blocks per CU (m114: separate
// blocks' waves co-schedule through each other's barrier stalls).
// Per tile: 12 ds_read + 32 MFMA per wave (1.65:1 compute-dominant); 6 stage
// loads/thread. Ledger (R6-verified single-phase):
//   top: lgkmcnt(0)+sched_barrier+s_barrier  (WAR: slot bs^1 reads closed)
//   stage(t+1, bs^1); s_waitcnt vmcnt(6)     (tile t's 6 loads landed)
//   s_barrier                                 (RAW for all waves)
//   12x ds_read_b128 + setprio'd 32 MFMA
// Row-major XCD chunk. NBN = #128-col panels (16 Q/proj, 8 KV).
// OUT 0: Q scatter. OUT 1: K|V split. OUT 2: proj fp32.
template <int NBN, int OUT>
static __device__ __forceinline__ void gemm_body(
    u16* sm, int bid, const u16* __restrict__ A, const u16* __restrict__ Wt,
    u16* __restrict__ Oa, u16* __restrict__ Ob2, float* __restrict__ OF) {
  const int tid = threadIdx.x;                  // 0..255
  const int lane = tid & 63, wid = tid >> 6;    // 4 waves
  const int wr = wid >> 1, wc = wid & 1;        // 2M x 2N
  const int l15 = lane & 15, l4 = lane >> 4;

  const int nwg = 32 * NBN;
  const int swz = (bid & 7) * (nwg >> 3) + (bid >> 3);  // XCD chunk (nwg%8==0)
  const int bm = swz / NBN, bn = swz % NBN;             // row-major
  const int m0 = bm * 256;
  const int n0r = bn * 128;

  auto pA = [&](int bs) { return sm + bs * 8192; };           // 256x32 = 16KB
  auto pB = [&](int bs) { return sm + 16384 + bs * 4096; };   // 128x32 = 8KB

  auto stage = [&](int kt, int bs) {
    const int kb = kt * 32;
#pragma unroll
    for (int c = 0; c < 4; ++c) {               // A: 1024 chunks / 256 thr
      int cidx = tid + c * 256;
      int r = cidx >> 2, q = cidx & 3;
      int cc = q ^ ((r >> 2) & 3);
      gload_lds16(A + (size_t)(m0 + r) * 2048 + kb + cc * 8, pA(bs) + cidx * 8);
    }
#pragma unroll
    for (int c = 0; c < 2; ++c) {               // B: 512 chunks
      int cidx = tid + c * 256;
      int r = cidx >> 2, q = cidx & 3;
      int cc = q ^ ((r >> 2) & 3);
      gload_lds16(Wt + (size_t)(n0r + r) * 2048 + kb + cc * 8, pB(bs) + cidx * 8);
    }
  };
  auto roff = [&](int fr, int c) {              // u16 index within a slot
    return (fr * 4 + (c ^ ((fr >> 2) & 3))) * 8;
  };

  const f4v Z4 = {0.f, 0.f, 0.f, 0.f};
  f4v acc[8][4];
#pragma unroll
  for (int i = 0; i < 8; i++)
#pragma unroll
    for (int j = 0; j < 4; j++) acc[i][j] = Z4;

  stage(0, 0);                                  // 6 loads in flight

  const int NT = 64;                            // 2048 / 32
  for (int t = 0; t < NT; ++t) {
    const int bs = t & 1;
    asm volatile("s_waitcnt lgkmcnt(0)" ::: "memory");
    __builtin_amdgcn_sched_barrier(0);
    asm volatile("s_barrier" ::: "memory");     // WAR: slot bs^1 reads closed
    if (t + 1 < NT) {
      stage(t + 1, bs ^ 1);
      asm volatile("s_waitcnt vmcnt(6)" ::: "memory");  // tile t landed
    } else {
      asm volatile("s_waitcnt vmcnt(0)" ::: "memory");
    }
    asm volatile("s_barrier" ::: "memory");     // RAW: ALL waves' tile t landed

    s8v a[8], b[4];
#pragma unroll
    for (int i = 0; i < 8; ++i)
      a[i] = *(const s8v*)&pA(bs)[roff(wr * 128 + i * 16 + l15, l4)];
#pragma unroll
    for (int j = 0; j < 4; ++j)
      b[j] = *(const s8v*)&pB(bs)[roff(wc * 64 + j * 16 + l15, l4)];
    __builtin_amdgcn_s_setprio(1);
#pragma unroll
    for (int i = 0; i < 8; ++i)
#pragma unroll
      for (int j = 0; j < 4; ++j)
        acc[i][j] = __builtin_amdgcn_mfma_f32_16x16x32_bf16(a[i], b[j], acc[i][j], 0, 0, 0);
    __builtin_amdgcn_s_setprio(0);
  }

  const int colg = bn * 128 + wc * 64;
  if constexpr (OUT == 0) {                     // Q: (B,16,L,128) bf16
    const int hh = colg >> 7, d0 = colg & 127;
#pragma unroll
    for (int i = 0; i < 8; i++)
#pragma unroll
      for (int r = 0; r < 4; r++) {
        int m = m0 + wr * 128 + i * 16 + l4 * 4 + r;
        int b2 = m >> 11, l = m & 2047;
        size_t base = ((size_t)(b2 * 16 + hh) * 2048 + l) * 128 + d0;
#pragma unroll
        for (int j = 0; j < 4; j++)
          Oa[base + j * 16 + l15] = f2bf(acc[i][j][r]);
      }
  } else if constexpr (OUT == 1) {              // K|V: (B,4,L,128) bf16 each
    u16* Ob = (colg < 512) ? Oa : Ob2;
    const int hh = (colg & 511) >> 7, d0 = colg & 127;
#pragma unroll
    for (int i = 0; i < 8; i++)
#pragma unroll
      for (int r = 0; r < 4; r++) {
        int m = m0 + wr * 128 + i * 16 + l4 * 4 + r;
        int b2 = m >> 11, l = m & 2047;
        size_t base = ((size_t)(b2 * 4 + hh) * 2048 + l) * 128 + d0;
#pragma unroll
        for (int j = 0; j < 4; j++)
          Ob[base + j * 16 + l15] = f2bf(acc[i][j][r]);
      }
  } else {                                      // proj: fp32 row-major
#pragma unroll
    for (int i = 0; i < 8; i++)
#pragma unroll
      for (int r = 0; r < 4; r++) {
        int m = m0 + wr * 128 + i * 16 + l4 * 4 + r;
#pragma unroll
        for (int j = 0; j < 4; j++)
          OF[(size_t)m * 2048 + colg + j * 16 + l15] = acc[i][j][r];
      }
  }
}

// ---------------- merged QKV GEMM: 768 blocks = 512 Q + 256 KV, 2 blocks/CU ----------------
__global__ __launch_bounds__(256, 2) void gemm_qkv(
    const u16* __restrict__ x, const u16* __restrict__ wq,
    const u16* __restrict__ wkv, u16* __restrict__ q,
    u16* __restrict__ kO, u16* __restrict__ vO) {
  __shared__ u16 smem[24576];                   // 48KB -> 2 blocks/CU
  const int bid = (int)blockIdx.x;
  if (bid < 512) gemm_body<16, 0>(smem, bid, x, wq, q, nullptr, nullptr);
  else           gemm_body<8, 1>(smem, bid - 512, x, wkv, kO, vO, nullptr);
}

// ---------------- proj GEMM: 512 blocks, 2 blocks/CU ----------------
__global__ __launch_bounds__(256, 2) void gemm_proj(
    const u16* __restrict__ y, const u16* __restrict__ wp, float* __restrict__ out) {
  __shared__ u16 smem[24576];
  gemm_body<16, 2>(smem, (int)blockIdx.x, y, wp, nullptr, nullptr, out);
}

// ---------------- merged K-norm + V-transpose (1280 blocks) ----------------
__global__ __launch_bounds__(256) void norm_transpose(
    u16* __restrict__ kbuf, const u16* __restrict__ v, u16* __restrict__ vt,
    const float* __restrict__ tc, const float* __restrict__ ts) {
  __shared__ u16 t[64][64];
  const int bid = (int)blockIdx.x;
  const int tid = threadIdx.x;
  if (bid < 1024) {
    const int l0 = (bid & 31) * 64, d0 = ((bid >> 5) & 1) * 64, bg = bid >> 6;
#pragma unroll
    for (int it = 0; it < 2; ++it) {
      int lin = it * 256 + tid;
      int r = lin >> 3, cb = lin & 7;
      s8v val = *(const s8v*)&v[((bg * 2048 + l0 + r) * 128) + d0 + cb * 8];
      *(s8v*)&t[r][(cb ^ (r & 7)) * 8] = val;
    }
    __syncthreads();
#pragma unroll
    for (int it = 0; it < 2; ++it) {
      int lin = it * 256 + tid;
      int r2 = lin >> 3, c2 = (lin & 7) * 8;
      s8v o;
#pragma unroll
      for (int j = 0; j < 8; ++j) {
        int rr = c2 + j, cc = r2;
        o[j] = (short)t[rr][(cc & 7) + 8 * ((cc >> 3) ^ (rr & 7))];
      }
      *(s8v*)&vt[((bg * 128 + d0 + r2) * 2048) + l0 + c2] = o;
    }
  } else {
    const int lane = tid & 63;
    const int gw = (bid - 1024) * 4 + (tid >> 6);
    for (int row = gw; row < 32768; row += 1024) {
      int l = row & 2047;
      u16* p = kbuf + (size_t)row * 128;
      float x1 = bf2f(p[lane]);
      float x2 = bf2f(p[lane + 64]);
      float ss = x1 * x1 + x2 * x2;
#pragma unroll
      for (int off = 32; off > 0; off >>= 1) ss += __shfl_xor(ss, off, 64);
      float r = rsqrtf(ss * (1.0f / 128.0f) + 1.1920929e-07f);
      x1 *= r; x2 *= r;
      if (l >= 16) {
        int tt = l - 16;
        float c = tc[tt * 64 + lane], s = ts[tt * 64 + lane];
        float o1 = x1 * c + x2 * s;
        float o2 = -x1 * s + x2 * c;
        x1 = o1; x2 = o2;
      }
      p[lane] = f2bf(x1);
      p[lane + 64] = f2bf(x2);
    }
  }
}

// ---------------- flash attention v3 (R16: full-width swizzle + tree softmax) ----------------
__global__ __launch_bounds__(512, 2) void attn(const u16* __restrict__ q,
                                               const u16* __restrict__ k,
                                               const u16* __restrict__ vt,
                                               u16* __restrict__ y,
                                               const float* __restrict__ qg,
                                               const float* __restrict__ tc,
                                               const float* __restrict__ ts) {
  __shared__ u16 lK[2][64 * 128];   // row kv: 16 chunks, phys = logical ^ (kv&15)
  __shared__ u16 lVT[2][64 * 128];  // line d>>1: 16 chunks, phys = ((d&1)*8+kc) ^ (line&15)
  const int tid = threadIdx.x;
  const int lane = tid & 63, wid = tid >> 6;
  const int l31 = lane & 31, hi = lane >> 5;

  const int bid = (int)blockIdx.x;                 // 0..255
  const int bg = (bid & 7) * 2 + (bid >> 7);       // XCD k hosts bg {2k,2k+1}
  const int pairi = (bid >> 3) & 15;               // 0..15
  const int b = bg >> 2, g = bg & 3;
  const int h = g * 4 + (wid & 3);
  const int se = wid >> 2;                         // row-half 0/1

  const u16* qh = q + (size_t)(b * 16 + h) * 2048 * 128;
  const u16* kb0 = k + (size_t)(b * 4 + g) * 2048 * 128;
  const u16* vtb0 = vt + (size_t)(b * 4 + g) * 128 * 2048;
  const float gscale = qg[h] * (0.08838834764831845f * 1.4426950408889634f);

  auto stage = [&](int t, int bufsel) {
    const int kv0 = t * 64;
#pragma unroll
    for (int it = 0; it < 2; ++it) {        // K tile 64x128 (16KB)
      int lin = it * 512 + tid;
      int kj = lin >> 4, s = lin & 15;
      gload_lds16(kb0 + (size_t)(kv0 + kj) * 128 + ((s ^ (kj & 15)) * 8),
                  &lK[bufsel][lin * 8]);
    }
#pragma unroll
    for (int it = 0; it < 2; ++it) {        // VT tile 128x64 (16KB), paired-d lines
      int lin = it * 512 + tid;
      int r = lin >> 4, c = lin & 15;
      int gl = c ^ (r & 15);
      int d = 2 * r + (gl >> 3);
      gload_lds16(vtb0 + (size_t)d * 2048 + kv0 + ((gl & 7) * 8),
                  &lVT[bufsel][lin * 8]);
    }
  };

  for (int ph = 0; ph < 2; ++ph) {
    const int qt = ph ? (31 - pairi) : pairi;
    const int q0 = qt * 64;
    const int nt = qt + 1;                  // KV tiles of 64
    const int pos = q0 + 32 * se + l31;

    // ---- fused Q: RMSNorm + RoPE + gain*(1/sqrt(128))*log2(e), pack B-frags ----
    s8v qf[8];
    {
      const u16* qp = qh + (size_t)pos * 128 + hi * 8;
      s8v qr[8];
#pragma unroll
      for (int ks = 0; ks < 8; ++ks) qr[ks] = *(const s8v*)&qp[ks * 16];
      float ssum = 0.f;
#pragma unroll
      for (int ks = 0; ks < 8; ++ks)
#pragma unroll
        for (int j = 0; j < 8; ++j) {
          float v = bf2f((u16)qr[ks][j]);
          ssum += v * v;
        }
      ssum += __shfl_xor(ssum, 32, 64);
      const float rn = rsqrtf(ssum * (1.0f / 128.0f) + 1.1920929e-07f) * gscale;
      const bool rot = (pos >= 16);
      const int tt = pos - 16;
#pragma unroll
      for (int ks = 0; ks < 4; ++ks) {
        float cv[8], sv[8];
        if (rot) {
          const float* cp = &tc[tt * 64 + ks * 16 + hi * 8];
          const float* sp = &ts[tt * 64 + ks * 16 + hi * 8];
          *(float4*)&cv[0] = *(const float4*)cp;
          *(float4*)&cv[4] = *(const float4*)(cp + 4);
          *(float4*)&sv[0] = *(const float4*)sp;
          *(float4*)&sv[4] = *(const float4*)(sp + 4);
        }
        uint32_t wlo[4], whi[4];
#pragma unroll
        for (int j2 = 0; j2 < 4; ++j2) {
          float o1[2], o2[2];
#pragma unroll
          for (int e = 0; e < 2; ++e) {
            const int j = j2 * 2 + e;
            float x1 = bf2f((u16)qr[ks][j]);
            float x2 = bf2f((u16)qr[ks + 4][j]);
            float a = x1, bb = x2;
            if (rot) { a = x1 * cv[j] + x2 * sv[j]; bb = x2 * cv[j] - x1 * sv[j]; }
            o1[e] = a * rn;
            o2[e] = bb * rn;
          }
          asm("v_cvt_pk_bf16_f32 %0, %1, %2" : "=v"(wlo[j2]) : "v"(o1[0]), "v"(o1[1]));
          asm("v_cvt_pk_bf16_f32 %0, %1, %2" : "=v"(whi[j2]) : "v"(o2[0]), "v"(o2[1]));
        }
        union { uint32_t u[4]; s8v v; } ua, ub;
        ua.u[0] = wlo[0]; ua.u[1] = wlo[1]; ua.u[2] = wlo[2]; ua.u[3] = wlo[3];
        ub.u[0] = whi[0]; ub.u[1] = whi[1]; ub.u[2] = whi[2]; ub.u[3] = whi[3];
        qf[ks] = ua.v;
        qf[ks + 4] = ub.v;
      }
    }

    f16v yacc[4];
#pragma unroll
    for (int j = 0; j < 4; ++j)
#pragma unroll
      for (int r = 0; r < 16; ++r) yacc[j][r] = 0.f;
    float mrow = -1e30f, lrow = 0.f;

    stage(0, 0);
    __syncthreads();

    for (int t = 0; t < nt; ++t) {
      const int cur = t & 1;
      if (t + 1 < nt) stage(t + 1, cur ^ 1);
      const int kv0 = t * 64;

      // ---- QK^T swapped: S^T[kv][q] in exp2 domain, two 32-kv chunks ----
      f16v s0a, s1a;
#pragma unroll
      for (int r = 0; r < 16; ++r) { s0a[r] = 0.f; s1a[r] = 0.f; }
      __builtin_amdgcn_s_setprio(1);
#pragma unroll
      for (int ks = 0; ks < 8; ++ks) {
        const int slot = (2 * ks + hi) ^ (l31 & 15);
        s8v kf0 = *(const s8v*)&lK[cur][(l31)*128 + slot * 8];
        s8v kf1 = *(const s8v*)&lK[cur][(32 + l31) * 128 + slot * 8];
        s0a = __builtin_amdgcn_mfma_f32_32x32x16_bf16(kf0, qf[ks], s0a, 0, 0, 0);
        s1a = __builtin_amdgcn_mfma_f32_32x32x16_bf16(kf1, qf[ks], s1a, 0, 0, 0);
      }
      __builtin_amdgcn_s_setprio(0);

      // ---- causal mask + row max (tree-reduced) ----
      const bool last = (t == nt - 1);
      float p0[16], p1[16], mx[16];
#pragma unroll
      for (int r = 0; r < 16; ++r) {
        const int kvloc = (r & 3) + 8 * (r >> 2) + 4 * hi;
        float v0 = s0a[r];
        float v1 = s1a[r];
        if (last) {
          if (kv0 + kvloc > pos) v0 = -1e30f;
          if (kv0 + 32 + kvloc > pos) v1 = -1e30f;
        }
        p0[r] = v0; p1[r] = v1;
        mx[r] = fmaxf(v0, v1);
      }
#pragma unroll
      for (int s2 = 8; s2 > 0; s2 >>= 1)
#pragma unroll
        for (int r = 0; r < s2; ++r) mx[r] = fmaxf(mx[r], mx[r + s2]);
      float pmax = fmaxf(mx[0], __shfl_xor(mx[0], 32, 64));

      // ---- defer-max (T13): THR = 8*log2e in exp2 domain ----
      if (!__all(pmax - mrow <= 11.541560327111707f)) {
        float mnew = fmaxf(mrow, pmax);
        float corr = __builtin_amdgcn_exp2f(mrow - mnew);
#pragma unroll
        for (int r = 0; r < 16; ++r) {
          const int qloc = (r & 3) + 8 * (r >> 2) + 4 * hi;
          float cb = __shfl(corr, qloc, 64);
          yacc[0][r] *= cb; yacc[1][r] *= cb; yacc[2][r] *= cb; yacc[3][r] *= cb;
        }
        lrow *= corr;
        mrow = mnew;
      }

      // ---- exp2 + fp32 row sum (tree-reduced) ----
      float sm[16];
#pragma unroll
      for (int r = 0; r < 16; ++r) {
        float e0 = __builtin_amdgcn_exp2f(p0[r] - mrow);
        float e1 = __builtin_amdgcn_exp2f(p1[r] - mrow);
        p0[r] = e0; p1[r] = e1;
        sm[r] = e0 + e1;
      }
#pragma unroll
      for (int s2 = 8; s2 > 0; s2 >>= 1)
#pragma unroll
        for (int r = 0; r < s2; ++r) sm[r] += sm[r + s2];
      float ps = sm[0] + __shfl_xor(sm[0], 32, 64);
      lrow += ps;

      // ---- PV: cvt_pk pack + permlane32_swap exchange + MFMA ----
      __builtin_amdgcn_s_setprio(1);
#pragma unroll
      for (int ks = 0; ks < 4; ++ks) {
        const float* pc = (ks < 2) ? p0 : p1;
        const int rb = 8 * (ks & 1);
        uint32_t A0, A1, B0, B1;
        asm("v_cvt_pk_bf16_f32 %0, %1, %2" : "=v"(A0) : "v"(pc[rb + 0]), "v"(pc[rb + 1]));
        asm("v_cvt_pk_bf16_f32 %0, %1, %2" : "=v"(A1) : "v"(pc[rb + 2]), "v"(pc[rb + 3]));
        asm("v_cvt_pk_bf16_f32 %0, %1, %2" : "=v"(B0) : "v"(pc[rb + 4]), "v"(pc[rb + 5]));
        asm("v_cvt_pk_bf16_f32 %0, %1, %2" : "=v"(B1) : "v"(pc[rb + 6]), "v"(pc[rb + 7]));
        // after swap: A0 = [A0_lo|B0_lo] = uu0, B0 = [A0_hi|B0_hi] = uu2 (ditto A1/B1)
        asm("v_permlane32_swap_b32 %0, %1" : "+v"(A0), "+v"(B0));
        asm("v_permlane32_swap_b32 %0, %1" : "+v"(A1), "+v"(B1));
        union { uint32_t u[4]; s8v v; } uu;
        uu.u[0] = A0; uu.u[1] = A1; uu.u[2] = B0; uu.u[3] = B1;
#pragma unroll
        for (int jd = 0; jd < 4; ++jd) {
          const int rowd = 32 * jd + l31;
          const int line = rowd >> 1;
          const int gl = ((rowd & 1) << 3) | (2 * ks + hi);
          const int c = gl ^ (line & 15);
          s8v vf = *(const s8v*)&lVT[cur][line * 128 + c * 8];
          yacc[jd] = __builtin_amdgcn_mfma_f32_32x32x16_bf16(uu.v, vf, yacc[jd], 0, 0, 0);
        }
      }
      __builtin_amdgcn_s_setprio(0);
      __syncthreads();
    }

    // ---- finalize: broadcast 1/l per C-row, write y (B,L,H*128) bf16 ----
    float inv = 1.0f / lrow;
#pragma unroll
    for (int r = 0; r < 16; ++r) {
      const int qloc = (r & 3) + 8 * (r >> 2) + 4 * hi;
      float ib = __shfl(inv, qloc, 64);
      const int qrow = q0 + 32 * se + qloc;
      size_t base = ((size_t)(b * 2048 + qrow)) * 2048 + h * 128 + l31;
#pragma unroll
      for (int jd = 0; jd < 4; ++jd)
        y[base + 32 * jd] = f2bf(yacc[jd][r] * ib);
    }
  }
}

extern "C" void kernel_launch(void* const* d_in, const int* in_sizes, int n_in,
                              void* d_out, int out_size, void* d_ws, size_t ws_size,
                              hipStream_t stream) {
  const float* x  = (const float*)d_in[0];
  const float* Wq = (const float*)d_in[1];
  const float* Wk = (const float*)d_in[2];
  const float* Wv = (const float*)d_in[3];
  const float* Wp = (const float*)d_in[4];
  const float* qg = (const float*)d_in[5];
  float* out = (float*)d_out;

  char* ws = (char*)d_ws;
  size_t off = 0;
  auto alloc = [&](size_t bytes) {
    void* p = ws + off;
    off += (bytes + 255) & ~(size_t)255;
    return p;
  };
  u16* x_bf  = (u16*)alloc((size_t)8192 * 2048 * 2);   // also reused as y_bf
  u16* wq_bf = (u16*)alloc((size_t)2048 * 2048 * 2);   // also reused as vt_bf
  u16* wk_bf = (u16*)alloc((size_t)512 * 2048 * 2);    // wk|wv contiguous = KV weight
  u16* wv_bf = (u16*)alloc((size_t)512 * 2048 * 2);
  u16* wp_bf = (u16*)alloc((size_t)2048 * 2048 * 2);
  u16* q_bf  = (u16*)alloc((size_t)4 * 16 * 2048 * 128 * 2);
  u16* k_bf  = (u16*)alloc((size_t)4 * 4 * 2048 * 128 * 2);
  u16* v_bf  = (u16*)alloc((size_t)4 * 4 * 2048 * 128 * 2);
  float* tab = (float*)alloc((size_t)2032 * 64 * 2 * 4);
  u16* y_bf  = x_bf;    // x dead after QKV GEMMs
  u16* vt_bf = wq_bf;   // Wq dead after Q GEMM (same size)
  (void)wv_bf;

  prep<<<2048, 256, 0, stream>>>((const float4*)x, (const float4*)Wq,
                                 (const float4*)Wk, (const float4*)Wv,
                                 (const float4*)Wp, (uint2*)x_bf, (uint2*)wq_bf,
                                 tab, tab + 2032 * 64);
  gemm_qkv<<<dim3(768), 256, 0, stream>>>(x_bf, wq_bf, wk_bf, q_bf, k_bf, v_bf);
  norm_transpose<<<dim3(1280), 256, 0, stream>>>(k_bf, v_bf, vt_bf,
                                                 tab, tab + 2032 * 64);
  attn<<<dim3(256), 512, 0, stream>>>(q_bf, k_bf, vt_bf, y_bf, qg,
                                      tab, tab + 2032 * 64);
  gemm_proj<<<dim3(512), 256, 0, stream>>>(y_bf, wp_bf, out);
}

// Round 19
// 324.543 us; speedup vs baseline: 1.0195x; 1.0195x over previous
//
#include <hip/hip_runtime.h>
#include <stdint.h>

// Shapes (fixed): B=4 L=2048 D=2048 H=16 KVH=4 HD=128 M=16 T=2032
typedef unsigned short u16;
typedef short s8v __attribute__((ext_vector_type(8)));   // 8 bf16 (4 VGPR) MFMA frag
typedef float f4v __attribute__((ext_vector_type(4)));   // 16x16 MFMA accum
typedef float f16v __attribute__((ext_vector_type(16))); // 32x32 MFMA accum

typedef __attribute__((address_space(1))) char gchar;
typedef __attribute__((address_space(3))) char lchar;

static __device__ __forceinline__ u16 f2bf(float f) {
  uint32_t x = __float_as_uint(f);
  x += 0x7fffu + ((x >> 16) & 1u);            // RNE
  return (u16)(x >> 16);
}
static __device__ __forceinline__ float bf2f(u16 u) {
  return __uint_as_float(((uint32_t)u) << 16);
}
// async global->LDS, 16B per lane. LDS dest must be wave-linear (base + lane*16).
static __device__ __forceinline__ void gload_lds16(const void* g, void* l) {
  __builtin_amdgcn_global_load_lds((gchar*)(uintptr_t)g,
                                   (lchar*)(uint32_t)(uintptr_t)l, 16, 0, 0);
}

// ---------------- prep: x->bf16, weights->bf16, rope table (one launch) ----------------
__global__ __launch_bounds__(256) void prep(const float4* __restrict__ x,
                                            const float4* __restrict__ wq,
                                            const float4* __restrict__ wk,
                                            const float4* __restrict__ wv,
                                            const float4* __restrict__ wp,
                                            uint2* __restrict__ xbf,
                                            uint2* __restrict__ wbf,
                                            float* __restrict__ tc,
                                            float* __restrict__ ts) {
  const int gid = blockIdx.x * 256 + threadIdx.x;
  const int st = gridDim.x * 256;
  for (int i = gid; i < 4194304; i += st) {            // x: 8192x2048 fp32
    float4 v = x[i];
    uint2 o;
    o.x = (uint32_t)f2bf(v.x) | ((uint32_t)f2bf(v.y) << 16);
    o.y = (uint32_t)f2bf(v.z) | ((uint32_t)f2bf(v.w) << 16);
    xbf[i] = o;
  }
  for (int i = gid; i < 2621440; i += st) {            // wq|wk|wv|wp contiguous dst
    const float4* s;
    int off;
    if (i < 1048576)      { s = wq; off = i; }
    else if (i < 1310720) { s = wk; off = i - 1048576; }
    else if (i < 1572864) { s = wv; off = i - 1310720; }
    else                  { s = wp; off = i - 1572864; }
    float4 v = s[off];
    uint2 o;
    o.x = (uint32_t)f2bf(v.x) | ((uint32_t)f2bf(v.y) << 16);
    o.y = (uint32_t)f2bf(v.z) | ((uint32_t)f2bf(v.w) << 16);
    wbf[i] = o;
  }
  for (int i = gid; i < 2032 * 64; i += st) {          // rope table [T][64]
    int t = i >> 6, f = i & 63;
    float invf = 1.0f / powf(10000.0f, (float)f * (1.0f / 64.0f));
    float ang = (float)t * invf;
    float s, c;
    sincosf(ang, &s, &c);
    tc[i] = c;
    ts[i] = s;
  }
}

// ---------------- gemm8 body v2: 256x256, K-half region phases ----------------
// regions [bs][ks] (A 16KB, B 16KB); phase ks: 12 ds_read (each frag ONCE),
// lgkmcnt(0)+sched_barrier+s_barrier (WAR), stage tile t+2's [A,B][ks] halves
// (4 loads) into just-freed region, setprio'd 32 MFMA. Tile top: vmcnt(8)
// (t+1's 8 loads in flight) + barrier (RAW). Row-major XCD chunk.
template <int OUT>
static __device__ __forceinline__ void gemm8_body(
    u16* sm, int bid, const u16* __restrict__ A, const u16* __restrict__ Wt,
    u16* __restrict__ Oa, float* __restrict__ OF) {
  const int tid = threadIdx.x;
  const int lane = tid & 63, wid = tid >> 6;
  const int wr = wid >> 2, wc = wid & 3;         // 2M x 4N, wave-tile 128x64
  const int l15 = lane & 15, l4 = lane >> 4;

  const int swz = (bid & 7) * 32 + (bid >> 3);   // XCD chunk (256-block path)
  const int bm = swz >> 3, bn = swz & 7;         // ROW-major: 4 A-rows per XCD
  const int m0 = bm * 256;
  const int n0r = bn * 256;

  auto pA = [&](int bs, int ks) { return sm + (bs * 2 + ks) * 8192; };
  auto pB = [&](int bs, int ks) { return sm + 32768 + (bs * 2 + ks) * 8192; };

  auto stage_part = [&](int kt, int bs, int ks) {
    const int kb = kt * 64 + ks * 32;
#pragma unroll
    for (int c = 0; c < 2; ++c) {                // A half: 256x32 = 1024 chunks
      int cidx = tid + c * 512;
      int r = cidx >> 2, q = cidx & 3;
      int cc = q ^ ((r >> 2) & 3);
      gload_lds16(A + (size_t)(m0 + r) * 2048 + kb + cc * 8,
                  pA(bs, ks) + cidx * 8);
    }
#pragma unroll
    for (int c = 0; c < 2; ++c) {                // B half: 256x32 = 1024 chunks
      int cidx = tid + c * 512;
      int r = cidx >> 2, q = cidx & 3;
      int cc = q ^ ((r >> 2) & 3);
      gload_lds16(Wt + (size_t)(n0r + r) * 2048 + kb + cc * 8,
                  pB(bs, ks) + cidx * 8);
    }
  };
  auto roff = [&](int fr, int c) {               // u16 index within a region
    return (fr * 4 + (c ^ ((fr >> 2) & 3))) * 8;
  };

  const f4v Z4 = {0.f, 0.f, 0.f, 0.f};
  f4v acc[8][4];
#pragma unroll
  for (int i = 0; i < 8; i++)
#pragma unroll
    for (int j = 0; j < 4; j++) acc[i][j] = Z4;

  // prologue: tiles 0,1 fully staged (16 loads/thread outstanding)
  stage_part(0, 0, 0); stage_part(0, 0, 1);
  stage_part(1, 1, 0); stage_part(1, 1, 1);

  const int NT = 32;                 // 2048 / 64
  for (int t = 0; t < NT; ++t) {
    const int bs = t & 1;
    if (t + 1 < NT) asm volatile("s_waitcnt vmcnt(8)" ::: "memory");
    else            asm volatile("s_waitcnt vmcnt(0)" ::: "memory");
    asm volatile("s_barrier" ::: "memory");      // RAW: ALL waves' tile t landed
    const bool pf = (t + 2 < NT);
#pragma unroll
    for (int ks = 0; ks < 2; ++ks) {
      s8v a[8], b[4];
#pragma unroll
      for (int i = 0; i < 8; ++i)
        a[i] = *(const s8v*)&pA(bs, ks)[roff(wr * 128 + i * 16 + l15, l4)];
#pragma unroll
      for (int j = 0; j < 4; ++j)
        b[j] = *(const s8v*)&pB(bs, ks)[roff(wc * 64 + j * 16 + l15, l4)];
      asm volatile("s_waitcnt lgkmcnt(0)" ::: "memory");
      __builtin_amdgcn_sched_barrier(0);
      asm volatile("s_barrier" ::: "memory");    // WAR: region [bs][ks] fully read
      if (pf) stage_part(t + 2, bs, ks);         // overwrite the freed region
      __builtin_amdgcn_s_setprio(1);
#pragma unroll
      for (int i = 0; i < 8; ++i)
#pragma unroll
        for (int j = 0; j < 4; ++j)
          acc[i][j] = __builtin_amdgcn_mfma_f32_16x16x32_bf16(a[i], b[j], acc[i][j], 0, 0, 0);
      __builtin_amdgcn_s_setprio(0);
      // no trailing barrier: next phase reads [bs][ks^1]; next tile gated at top
    }
  }

  const int colg = bn * 256 + wc * 64;
  if constexpr (OUT == 0) {                      // Q: (B,16,L,128) bf16
    const int hh = colg >> 7, d0 = colg & 127;
#pragma unroll
    for (int i = 0; i < 8; i++)
#pragma unroll
      for (int r = 0; r < 4; r++) {
        int m = m0 + wr * 128 + i * 16 + l4 * 4 + r;
        int b2 = m >> 11, l = m & 2047;
        size_t base = ((size_t)(b2 * 16 + hh) * 2048 + l) * 128 + d0;
#pragma unroll
        for (int j = 0; j < 4; j++)
          Oa[base + j * 16 + l15] = f2bf(acc[i][j][r]);
      }
  } else {                                       // proj: fp32 row-major
#pragma unroll
    for (int i = 0; i < 8; i++)
#pragma unroll
      for (int r = 0; r < 4; r++) {
        int m = m0 + wr * 128 + i * 16 + l4 * 4 + r;
#pragma unroll
        for (int j = 0; j < 4; j++)
          OF[(size_t)m * 2048 + colg + j * 16 + l15] = acc[i][j][r];
      }
  }
}

// ---------------- gemm_kv body: 256x128 region structure (R10, row-major XCD) ----------------
static __device__ __forceinline__ void gemm_kv_body(
    u16* sm, int bid, const u16* __restrict__ A, const u16* __restrict__ Wt,
    u16* __restrict__ Oa, u16* __restrict__ Ob2) {
  constexpr int MI = 4;
  const int tid = threadIdx.x;
  const int lane = tid & 63, wid = tid >> 6;
  const int wr = wid >> 1, wc = wid & 1;
  const int l15 = lane & 15, l4 = lane >> 4;

  const int swz = (bid & 7) * 32 + (bid >> 3);
  const int bm = swz >> 3, bn = swz & 7;         // ROW-major chunk
  const int m0 = bm * 256;
  const int n0r = bn * 128;

  auto pA = [&](int bs, int ks) { return sm + (bs * 2 + ks) * 8192; };
  auto pB = [&](int bs, int ks) { return sm + 32768 + (bs * 2 + ks) * 4096; };

  auto stage_part = [&](int kt, int bs, int ks) {
    const int kb = kt * 64 + ks * 32;
#pragma unroll
    for (int c = 0; c < 2; ++c) {
      int cidx = tid + c * 512;
      int r = cidx >> 2, q = cidx & 3;
      int cc = q ^ ((r >> 2) & 3);
      gload_lds16(A + (size_t)(m0 + r) * 2048 + kb + cc * 8,
                  pA(bs, ks) + cidx * 8);
    }
    {
      int cidx = tid;
      int r = cidx >> 2, q = cidx & 3;
      int cc = q ^ ((r >> 2) & 3);
      gload_lds16(Wt + (size_t)(n0r + r) * 2048 + kb + cc * 8,
                  pB(bs, ks) + cidx * 8);
    }
  };
  auto roff = [&](int fr, int c) {
    return (fr * 4 + (c ^ ((fr >> 2) & 3))) * 8;
  };

  const f4v Z4 = {0.f, 0.f, 0.f, 0.f};
  f4v acc[MI][4];
#pragma unroll
  for (int i = 0; i < MI; i++)
#pragma unroll
    for (int j = 0; j < 4; j++) acc[i][j] = Z4;

  stage_part(0, 0, 0); stage_part(0, 0, 1);
  stage_part(1, 1, 0); stage_part(1, 1, 1);

  const int NT = 32;
  for (int t = 0; t < NT; ++t) {
    const int bs = t & 1;
    if (t + 1 < NT) asm volatile("s_waitcnt vmcnt(6)" ::: "memory");
    else            asm volatile("s_waitcnt vmcnt(0)" ::: "memory");
    asm volatile("s_barrier" ::: "memory");
    const bool pf = (t + 2 < NT);
#pragma unroll
    for (int ks = 0; ks < 2; ++ks) {
      s8v afrg[MI], bfrg[4];
#pragma unroll
      for (int i = 0; i < MI; ++i)
        afrg[i] = *(const s8v*)&pA(bs, ks)[roff(wr * (MI * 16) + i * 16 + l15, l4)];
#pragma unroll
      for (int j = 0; j < 4; ++j)
        bfrg[j] = *(const s8v*)&pB(bs, ks)[roff(wc * 64 + j * 16 + l15, l4)];
      asm volatile("s_waitcnt lgkmcnt(0)" ::: "memory");
      __builtin_amdgcn_sched_barrier(0);
      asm volatile("s_barrier" ::: "memory");
      if (pf) stage_part(t + 2, bs, ks);
      __builtin_amdgcn_s_setprio(1);
#pragma unroll
      for (int i = 0; i < MI; ++i)
#pragma unroll
        for (int j = 0; j < 4; ++j)
          acc[i][j] = __builtin_amdgcn_mfma_f32_16x16x32_bf16(afrg[i], bfrg[j], acc[i][j], 0, 0, 0);
      __builtin_amdgcn_s_setprio(0);
    }
  }

  const int colg = bn * 128 + wc * 64;
  u16* Ob = (colg < 512) ? Oa : Ob2;
  const int hh = (colg & 511) >> 7, d0 = colg & 127;
#pragma unroll
  for (int i = 0; i < MI; i++)
#pragma unroll
    for (int r = 0; r < 4; r++) {
      int m = m0 + wr * (MI * 16) + i * 16 + l4 * 4 + r;
      int b = m >> 11, l = m & 2047;
      size_t base = ((size_t)(b * 4 + hh) * 2048 + l) * 128 + d0;
#pragma unroll
      for (int j = 0; j < 4; j++)
        Ob[base + j * 16 + l15] = f2bf(acc[i][j][r]);
    }
}

// ---------------- merged QKV GEMM: 512 blocks = 256 Q-path + 256 KV-path ----------------
__global__ __launch_bounds__(512, 2) void gemm_qkv(
    const u16* __restrict__ x, const u16* __restrict__ wq,
    const u16* __restrict__ wkv, u16* __restrict__ q,
    u16* __restrict__ kO, u16* __restrict__ vO) {
  __shared__ u16 smem[65536];                    // 128KB arena (both paths fit)
  const int bid = (int)blockIdx.x;
  if (bid < 256) gemm8_body<0>(smem, bid, x, wq, q, nullptr);
  else           gemm_kv_body(smem, bid - 256, x, wkv, kO, vO);
}

// ---------------- proj GEMM (gemm8 path, own launch) ----------------
__global__ __launch_bounds__(512, 2) void gemm_proj(
    const u16* __restrict__ y, const u16* __restrict__ wp, float* __restrict__ out) {
  __shared__ u16 smem[65536];
  gemm8_body<2>(smem, (int)blockIdx.x, y, wp, nullptr, out);
}

// ---------------- merged K-norm + V-transpose (1280 blocks) ----------------
__global__ __launch_bounds__(256) void norm_transpose(
    u16* __restrict__ kbuf, const u16* __restrict__ v, u16* __restrict__ vt,
    const float* __restrict__ tc, const float* __restrict__ ts) {
  __shared__ u16 t[64][64];
  const int bid = (int)blockIdx.x;
  const int tid = threadIdx.x;
  if (bid < 1024) {
    const int l0 = (bid & 31) * 64, d0 = ((bid >> 5) & 1) * 64, bg = bid >> 6;
#pragma unroll
    for (int it = 0; it < 2; ++it) {
      int lin = it * 256 + tid;
      int r = lin >> 3, cb = lin & 7;
      s8v val = *(const s8v*)&v[((bg * 2048 + l0 + r) * 128) + d0 + cb * 8];
      *(s8v*)&t[r][(cb ^ (r & 7)) * 8] = val;
    }
    __syncthreads();
#pragma unroll
    for (int it = 0; it < 2; ++it) {
      int lin = it * 256 + tid;
      int r2 = lin >> 3, c2 = (lin & 7) * 8;
      s8v o;
#pragma unroll
      for (int j = 0; j < 8; ++j) {
        int rr = c2 + j, cc = r2;
        o[j] = (short)t[rr][(cc & 7) + 8 * ((cc >> 3) ^ (rr & 7))];
      }
      *(s8v*)&vt[((bg * 128 + d0 + r2) * 2048) + l0 + c2] = o;
    }
  } else {
    const int lane = tid & 63;
    const int gw = (bid - 1024) * 4 + (tid >> 6);
    for (int row = gw; row < 32768; row += 1024) {
      int l = row & 2047;
      u16* p = kbuf + (size_t)row * 128;
      float x1 = bf2f(p[lane]);
      float x2 = bf2f(p[lane + 64]);
      float ss = x1 * x1 + x2 * x2;
#pragma unroll
      for (int off = 32; off > 0; off >>= 1) ss += __shfl_xor(ss, off, 64);
      float r = rsqrtf(ss * (1.0f / 128.0f) + 1.1920929e-07f);
      x1 *= r; x2 *= r;
      if (l >= 16) {
        int tt = l - 16;
        float c = tc[tt * 64 + lane], s = ts[tt * 64 + lane];
        float o1 = x1 * c + x2 * s;
        float o2 = -x1 * s + x2 * c;
        x1 = o1; x2 = o2;
      }
      p[lane] = f2bf(x1);
      p[lane + 64] = f2bf(x2);
    }
  }
}

// ---------------- flash attention v3 (full-width swizzle + tree softmax) ----------------
__global__ __launch_bounds__(512, 2) void attn(const u16* __restrict__ q,
                                               const u16* __restrict__ k,
                                               const u16* __restrict__ vt,
                                               u16* __restrict__ y,
                                               const float* __restrict__ qg,
                                               const float* __restrict__ tc,
                                               const float* __restrict__ ts) {
  __shared__ u16 lK[2][64 * 128];   // row kv: 16 chunks, phys = logical ^ (kv&15)
  __shared__ u16 lVT[2][64 * 128];  // line d>>1: 16 chunks, phys = ((d&1)*8+kc) ^ (line&15)
  const int tid = threadIdx.x;
  const int lane = tid & 63, wid = tid >> 6;
  const int l31 = lane & 31, hi = lane >> 5;

  const int bid = (int)blockIdx.x;                 // 0..255
  const int bg = (bid & 7) * 2 + (bid >> 7);       // XCD k hosts bg {2k,2k+1}
  const int pairi = (bid >> 3) & 15;               // 0..15
  const int b = bg >> 2, g = bg & 3;
  const int h = g * 4 + (wid & 3);
  const int se = wid >> 2;                         // row-half 0/1

  const u16* qh = q + (size_t)(b * 16 + h) * 2048 * 128;
  const u16* kb0 = k + (size_t)(b * 4 + g) * 2048 * 128;
  const u16* vtb0 = vt + (size_t)(b * 4 + g) * 128 * 2048;
  const float gscale = qg[h] * (0.08838834764831845f * 1.4426950408889634f);

  auto stage = [&](int t, int bufsel) {
    const int kv0 = t * 64;
#pragma unroll
    for (int it = 0; it < 2; ++it) {        // K tile 64x128 (16KB)
      int lin = it * 512 + tid;
      int kj = lin >> 4, s = lin & 15;
      gload_lds16(kb0 + (size_t)(kv0 + kj) * 128 + ((s ^ (kj & 15)) * 8),
                  &lK[bufsel][lin * 8]);
    }
#pragma unroll
    for (int it = 0; it < 2; ++it) {        // VT tile 128x64 (16KB), paired-d lines
      int lin = it * 512 + tid;
      int r = lin >> 4, c = lin & 15;
      int gl = c ^ (r & 15);
      int d = 2 * r + (gl >> 3);
      gload_lds16(vtb0 + (size_t)d * 2048 + kv0 + ((gl & 7) * 8),
                  &lVT[bufsel][lin * 8]);
    }
  };

  for (int ph = 0; ph < 2; ++ph) {
    const int qt = ph ? (31 - pairi) : pairi;
    const int q0 = qt * 64;
    const int nt = qt + 1;                  // KV tiles of 64
    const int pos = q0 + 32 * se + l31;

    // ---- fused Q: RMSNorm + RoPE + gain*(1/sqrt(128))*log2(e), pack B-frags ----
    s8v qf[8];
    {
      const u16* qp = qh + (size_t)pos * 128 + hi * 8;
      s8v qr[8];
#pragma unroll
      for (int ks = 0; ks < 8; ++ks) qr[ks] = *(const s8v*)&qp[ks * 16];
      float ssum = 0.f;
#pragma unroll
      for (int ks = 0; ks < 8; ++ks)
#pragma unroll
        for (int j = 0; j < 8; ++j) {
          float v = bf2f((u16)qr[ks][j]);
          ssum += v * v;
        }
      ssum += __shfl_xor(ssum, 32, 64);
      const float rn = rsqrtf(ssum * (1.0f / 128.0f) + 1.1920929e-07f) * gscale;
      const bool rot = (pos >= 16);
      const int tt = pos - 16;
#pragma unroll
      for (int ks = 0; ks < 4; ++ks) {
        float cv[8], sv[8];
        if (rot) {
          const float* cp = &tc[tt * 64 + ks * 16 + hi * 8];
          const float* sp = &ts[tt * 64 + ks * 16 + hi * 8];
          *(float4*)&cv[0] = *(const float4*)cp;
          *(float4*)&cv[4] = *(const float4*)(cp + 4);
          *(float4*)&sv[0] = *(const float4*)sp;
          *(float4*)&sv[4] = *(const float4*)(sp + 4);
        }
        uint32_t wlo[4], whi[4];
#pragma unroll
        for (int j2 = 0; j2 < 4; ++j2) {
          float o1[2], o2[2];
#pragma unroll
          for (int e = 0; e < 2; ++e) {
            const int j = j2 * 2 + e;
            float x1 = bf2f((u16)qr[ks][j]);
            float x2 = bf2f((u16)qr[ks + 4][j]);
            float a = x1, bb = x2;
            if (rot) { a = x1 * cv[j] + x2 * sv[j]; bb = x2 * cv[j] - x1 * sv[j]; }
            o1[e] = a * rn;
            o2[e] = bb * rn;
          }
          asm("v_cvt_pk_bf16_f32 %0, %1, %2" : "=v"(wlo[j2]) : "v"(o1[0]), "v"(o1[1]));
          asm("v_cvt_pk_bf16_f32 %0, %1, %2" : "=v"(whi[j2]) : "v"(o2[0]), "v"(o2[1]));
        }
        union { uint32_t u[4]; s8v v; } ua, ub;
        ua.u[0] = wlo[0]; ua.u[1] = wlo[1]; ua.u[2] = wlo[2]; ua.u[3] = wlo[3];
        ub.u[0] = whi[0]; ub.u[1] = whi[1]; ub.u[2] = whi[2]; ub.u[3] = whi[3];
        qf[ks] = ua.v;
        qf[ks + 4] = ub.v;
      }
    }

    f16v yacc[4];
#pragma unroll
    for (int j = 0; j < 4; ++j)
#pragma unroll
      for (int r = 0; r < 16; ++r) yacc[j][r] = 0.f;
    float mrow = -1e30f, lrow = 0.f;

    stage(0, 0);
    __syncthreads();

    for (int t = 0; t < nt; ++t) {
      const int cur = t & 1;
      if (t + 1 < nt) stage(t + 1, cur ^ 1);
      const int kv0 = t * 64;

      // ---- QK^T swapped: S^T[kv][q] in exp2 domain, two 32-kv chunks ----
      f16v s0a, s1a;
#pragma unroll
      for (int r = 0; r < 16; ++r) { s0a[r] = 0.f; s1a[r] = 0.f; }
      __builtin_amdgcn_s_setprio(1);
#pragma unroll
      for (int ks = 0; ks < 8; ++ks) {
        const int slot = (2 * ks + hi) ^ (l31 & 15);
        s8v kf0 = *(const s8v*)&lK[cur][(l31)*128 + slot * 8];
        s8v kf1 = *(const s8v*)&lK[cur][(32 + l31) * 128 + slot * 8];
        s0a = __builtin_amdgcn_mfma_f32_32x32x16_bf16(kf0, qf[ks], s0a, 0, 0, 0);
        s1a = __builtin_amdgcn_mfma_f32_32x32x16_bf16(kf1, qf[ks], s1a, 0, 0, 0);
      }
      __builtin_amdgcn_s_setprio(0);

      // ---- causal mask + row max (tree-reduced) ----
      const bool last = (t == nt - 1);
      float p0[16], p1[16], mx[16];
#pragma unroll
      for (int r = 0; r < 16; ++r) {
        const int kvloc = (r & 3) + 8 * (r >> 2) + 4 * hi;
        float v0 = s0a[r];
        float v1 = s1a[r];
        if (last) {
          if (kv0 + kvloc > pos) v0 = -1e30f;
          if (kv0 + 32 + kvloc > pos) v1 = -1e30f;
        }
        p0[r] = v0; p1[r] = v1;
        mx[r] = fmaxf(v0, v1);
      }
#pragma unroll
      for (int s2 = 8; s2 > 0; s2 >>= 1)
#pragma unroll
        for (int r = 0; r < s2; ++r) mx[r] = fmaxf(mx[r], mx[r + s2]);
      float pmax = fmaxf(mx[0], __shfl_xor(mx[0], 32, 64));

      // ---- defer-max (T13): THR = 8*log2e in exp2 domain ----
      if (!__all(pmax - mrow <= 11.541560327111707f)) {
        float mnew = fmaxf(mrow, pmax);
        float corr = __builtin_amdgcn_exp2f(mrow - mnew);
#pragma unroll
        for (int r = 0; r < 16; ++r) {
          const int qloc = (r & 3) + 8 * (r >> 2) + 4 * hi;
          float cb = __shfl(corr, qloc, 64);
          yacc[0][r] *= cb; yacc[1][r] *= cb; yacc[2][r] *= cb; yacc[3][r] *= cb;
        }
        lrow *= corr;
        mrow = mnew;
      }

      // ---- exp2 + fp32 row sum (tree-reduced) ----
      float sm[16];
#pragma unroll
      for (int r = 0; r < 16; ++r) {
        float e0 = __builtin_amdgcn_exp2f(p0[r] - mrow);
        float e1 = __builtin_amdgcn_exp2f(p1[r] - mrow);
        p0[r] = e0; p1[r] = e1;
        sm[r] = e0 + e1;
      }
#pragma unroll
      for (int s2 = 8; s2 > 0; s2 >>= 1)
#pragma unroll
        for (int r = 0; r < s2; ++r) sm[r] += sm[r + s2];
      float ps = sm[0] + __shfl_xor(sm[0], 32, 64);
      lrow += ps;

      // ---- PV: cvt_pk pack + permlane32_swap exchange + MFMA ----
      __builtin_amdgcn_s_setprio(1);
#pragma unroll
      for (int ks = 0; ks < 4; ++ks) {
        const float* pc = (ks < 2) ? p0 : p1;
        const int rb = 8 * (ks & 1);
        uint32_t A0, A1, B0, B1;
        asm("v_cvt_pk_bf16_f32 %0, %1, %2" : "=v"(A0) : "v"(pc[rb + 0]), "v"(pc[rb + 1]));
        asm("v_cvt_pk_bf16_f32 %0, %1, %2" : "=v"(A1) : "v"(pc[rb + 2]), "v"(pc[rb + 3]));
        asm("v_cvt_pk_bf16_f32 %0, %1, %2" : "=v"(B0) : "v"(pc[rb + 4]), "v"(pc[rb + 5]));
        asm("v_cvt_pk_bf16_f32 %0, %1, %2" : "=v"(B1) : "v"(pc[rb + 6]), "v"(pc[rb + 7]));
        // after swap: A0 = [A0_lo|B0_lo] = uu0, B0 = [A0_hi|B0_hi] = uu2 (ditto A1/B1)
        asm("v_permlane32_swap_b32 %0, %1" : "+v"(A0), "+v"(B0));
        asm("v_permlane32_swap_b32 %0, %1" : "+v"(A1), "+v"(B1));
        union { uint32_t u[4]; s8v v; } uu;
        uu.u[0] = A0; uu.u[1] = A1; uu.u[2] = B0; uu.u[3] = B1;
#pragma unroll
        for (int jd = 0; jd < 4; ++jd) {
          const int rowd = 32 * jd + l31;
          const int line = rowd >> 1;
          const int gl = ((rowd & 1) << 3) | (2 * ks + hi);
          const int c = gl ^ (line & 15);
          s8v vf = *(const s8v*)&lVT[cur][line * 128 + c * 8];
          yacc[jd] = __builtin_amdgcn_mfma_f32_32x32x16_bf16(uu.v, vf, yacc[jd], 0, 0, 0);
        }
      }
      __builtin_amdgcn_s_setprio(0);
      __syncthreads();
    }

    // ---- finalize: broadcast 1/l per C-row, write y (B,L,H*128) bf16 ----
    float inv = 1.0f / lrow;
#pragma unroll
    for (int r = 0; r < 16; ++r) {
      const int qloc = (r & 3) + 8 * (r >> 2) + 4 * hi;
      float ib = __shfl(inv, qloc, 64);
      const int qrow = q0 + 32 * se + qloc;
      size_t base = ((size_t)(b * 2048 + qrow)) * 2048 + h * 128 + l31;
#pragma unroll
      for (int jd = 0; jd < 4; ++jd)
        y[base + 32 * jd] = f2bf(yacc[jd][r] * ib);
    }
  }
}

extern "C" void kernel_launch(void* const* d_in, const int* in_sizes, int n_in,
                              void* d_out, int out_size, void* d_ws, size_t ws_size,
                              hipStream_t stream) {
  const float* x  = (const float*)d_in[0];
  const float* Wq = (const float*)d_in[1];
  const float* Wk = (const float*)d_in[2];
  const float* Wv = (const float*)d_in[3];
  const float* Wp = (const float*)d_in[4];
  const float* qg = (const float*)d_in[5];
  float* out = (float*)d_out;

  char* ws = (char*)d_ws;
  size_t off = 0;
  auto alloc = [&](size_t bytes) {
    void* p = ws + off;
    off += (bytes + 255) & ~(size_t)255;
    return p;
  };
  u16* x_bf  = (u16*)alloc((size_t)8192 * 2048 * 2);   // also reused as y_bf
  u16* wq_bf = (u16*)alloc((size_t)2048 * 2048 * 2);   // also reused as vt_bf
  u16* wk_bf = (u16*)alloc((size_t)512 * 2048 * 2);    // wk|wv contiguous = KV weight
  u16* wv_bf = (u16*)alloc((size_t)512 * 2048 * 2);
  u16* wp_bf = (u16*)alloc((size_t)2048 * 2048 * 2);
  u16* q_bf  = (u16*)alloc((size_t)4 * 16 * 2048 * 128 * 2);
  u16* k_bf  = (u16*)alloc((size_t)4 * 4 * 2048 * 128 * 2);
  u16* v_bf  = (u16*)alloc((size_t)4 * 4 * 2048 * 128 * 2);
  float* tab = (float*)alloc((size_t)2032 * 64 * 2 * 4);
  u16* y_bf  = x_bf;    // x dead after QKV GEMMs
  u16* vt_bf = wq_bf;   // Wq dead after Q GEMM (same size)
  (void)wv_bf;

  prep<<<2048, 256, 0, stream>>>((const float4*)x, (const float4*)Wq,
                                 (const float4*)Wk, (const float4*)Wv,
                                 (const float4*)Wp, (uint2*)x_bf, (uint2*)wq_bf,
                                 tab, tab + 2032 * 64);
  gemm_qkv<<<dim3(512), 512, 0, stream>>>(x_bf, wq_bf, wk_bf, q_bf, k_bf, v_bf);
  norm_transpose<<<dim3(1280), 256, 0, stream>>>(k_bf, v_bf, vt_bf,
                                                 tab, tab + 2032 * 64);
  attn<<<dim3(256), 512, 0, stream>>>(q_bf, k_bf, vt_bf, y_bf, qg,
                                      tab, tab + 2032 * 64);
  gemm_proj<<<dim3(256), 512, 0, stream>>>(y_bf, wp_bf, out);
}